// Round 10
// baseline (991.012 us; speedup 1.0000x reference)
//
#include <hip/hip_runtime.h>
#include <hip/hip_bf16.h>
#include <stdint.h>

// Problem constants
#define BB   8192   // batch
#define DD   8      // features
#define PP   10     // poly basis width
#define RR   512    // TT rank
#define OUTD 64     // output dim
#define KK   5120   // expanded K = PP*RR
#define NBLK 512    // persistent grid size (2 blocks/CU on 256 CUs)

typedef __bf16 bf16x8 __attribute__((ext_vector_type(8)));
typedef float  f32x4  __attribute__((ext_vector_type(4)));

// Single-use grid barrier: counters zeroed by hipMemsetAsync before launch.
// Device-scope atomics (m20: atomicAdd on global is device scope); bounded
// spin so a co-residency failure manifests as wrong output, not a hang.
__device__ __forceinline__ void grid_sync(int* cnt, int idx) {
    __syncthreads();
    if (threadIdx.x == 0) {
        __threadfence();
        __hip_atomic_fetch_add(cnt + idx, 1, __ATOMIC_RELEASE,
                               __HIP_MEMORY_SCOPE_AGENT);
        int tries = 0;
        while (__hip_atomic_load(cnt + idx, __ATOMIC_ACQUIRE,
                                 __HIP_MEMORY_SCOPE_AGENT) < NBLK
               && tries < (1 << 24)) {
            __builtin_amdgcn_s_sleep(2);
            ++tries;
        }
        __threadfence();
    }
    __syncthreads();
}

// ---------------------------------------------------------------------------
// Persistent kernel: pack -> first -> 6 Horner mids -> last, grid barriers
// between phases. All fragment arrays compile-time indexed (round-4 lesson).
// ---------------------------------------------------------------------------
__global__ __launch_bounds__(256, 2) void tt_mega(
        const float* __restrict__ z, const float* __restrict__ G0,
        const float* __restrict__ Gmid, const float* __restrict__ Glast,
        float* __restrict__ out,
        __hip_bfloat16* resX, __hip_bfloat16* resY,
        __hip_bfloat16* tBf, __hip_bfloat16* tBlf,
        float* tG0, int* cnt) {
    __shared__ char smraw[33280] __attribute__((aligned(16)));

    const int bid  = blockIdx.x;
    const int tid  = threadIdx.x;
    const int lane = tid & 63;
    const int wave = tid >> 6;
    const int r16  = lane & 15;
    const int quad = lane >> 4;

    // ======================= Phase 0: fragment pack ========================
    // Mid units u<960: (c,j,kc) -> 32 i-rows x 512 n.  Last units 960..969:
    // j, looping kc internally.  bid 458 additionally computes tanh(G0).
    {
        __hip_bfloat16* sT = (__hip_bfloat16*)smraw;
        #pragma unroll 1
        for (int u = bid; u < 970; u += NBLK) {
            __syncthreads();
            if (u < 960) {
                const int c = u / 160, rem = u - c * 160;
                const int j = rem >> 4, kc = rem & 15;
                const float* Gp = Gmid + (size_t)c * (512 * 5120);
                __hip_bfloat16* db = tBf + (size_t)c * (RR * KK)
                                   + (size_t)(j * 16 + kc) * 16384;
                #pragma unroll
                for (int e = 0; e < 16; ++e) {
                    const int idx = (e * 256 + tid) * 4;
                    const int row = idx >> 9, col = idx & 511;
                    f32x4 v = *(const f32x4*)(Gp + (size_t)(kc * 32 + row) * 5120
                                              + (size_t)j * 512 + col);
                    __hip_bfloat16* sp = sT + row * 520 + col;
                    sp[0] = __float2bfloat16(tanhf(v.x));
                    sp[1] = __float2bfloat16(tanhf(v.y));
                    sp[2] = __float2bfloat16(tanhf(v.z));
                    sp[3] = __float2bfloat16(tanhf(v.w));
                }
                __syncthreads();
                #pragma unroll
                for (int cc = 0; cc < 8; ++cc) {
                    const int ch = cc * 256 + tid;
                    const int nt = ch >> 6, l = ch & 63;
                    const int r0 = (l >> 4) * 8, cb = nt * 16 + (l & 15);
                    union { __hip_bfloat16 h[8]; uint4 u4; } pk;
                    #pragma unroll
                    for (int e = 0; e < 8; ++e) pk.h[e] = sT[(r0 + e) * 520 + cb];
                    *(uint4*)(db + (size_t)ch * 8) = pk.u4;
                }
            } else {
                const int j = u - 960;
                #pragma unroll 1
                for (int kc = 0; kc < 16; ++kc) {
                    __syncthreads();
                    #pragma unroll
                    for (int it = 0; it < 2; ++it) {
                        const int idx = (it * 256 + tid) * 4;
                        const int row = idx >> 6, col = idx & 63;
                        f32x4 v = *(const f32x4*)(Glast
                                   + (size_t)(kc * 32 + row) * 640
                                   + (size_t)j * 64 + col);
                        __hip_bfloat16* sp = sT + row * 72 + col;
                        sp[0] = __float2bfloat16(tanhf(v.x));
                        sp[1] = __float2bfloat16(tanhf(v.y));
                        sp[2] = __float2bfloat16(tanhf(v.z));
                        sp[3] = __float2bfloat16(tanhf(v.w));
                    }
                    __syncthreads();
                    {
                        const int ch = tid;
                        const int nt = ch >> 6, l = ch & 63;
                        const int r0 = (l >> 4) * 8, cb = nt * 16 + (l & 15);
                        union { __hip_bfloat16 h[8]; uint4 u4; } pk;
                        #pragma unroll
                        for (int e = 0; e < 8; ++e) pk.h[e] = sT[(r0 + e) * 72 + cb];
                        *(uint4*)(tBlf + (size_t)(j * 16 + kc) * 2048
                                  + (size_t)ch * 8) = pk.u4;
                    }
                }
            }
        }
        if (bid == 458) {
            for (int x = tid; x < 5120; x += 256) tG0[x] = tanhf(G0[x]);
        }
    }
    grid_sync(cnt, 0);

    // ======================= Phase 1: first core ===========================
    {
        const int g = bid * 256 + tid;
        const int r = g & 511;
        const int brow = g >> 9;
        float tg[10];
        #pragma unroll
        for (int j = 0; j < 10; ++j) tg[j] = tG0[j * 512 + r];
        #pragma unroll 1
        for (int it = 0; it < 32; ++it) {
            const int b = brow + it * 256;
            const float z0 = z[(size_t)b * DD];
            float acc = tg[9];
            #pragma unroll
            for (int j = 8; j >= 0; --j) acc = acc * z0 + tg[j];
            resX[(size_t)b * RR + r] = __float2bfloat16(acc);
        }
    }
    grid_sync(cnt, 1);

    // ======================= Phases 2..7: mid cores ========================
    // Round-8 structure: m0 = (bid&127)*64, nb = (bid>>7) + h*4 (two halves,
    // A regs shared). K split across 4 waves; depth-3 B prefetch ring.
    {
        f32x4* redp = (f32x4*)smraw;          // [2][16][64]
        float* rc   = (float*)smraw;          // [64][64]
        constexpr size_t SKM = 16384;         // elems per K32 slab (32 n-tiles)
        constexpr size_t PJM = 16 * SKM;      // elems per j panel
        const int m0  = (bid & 127) * 64;
        const int nbb = bid >> 7;

        #pragma unroll 1
        for (int c = 0; c < 6; ++c) {
            const __hip_bfloat16* rin  = (c & 1) ? resY : resX;
            __hip_bfloat16*       rout = (c & 1) ? resX : resY;
            const __hip_bfloat16* tB = tBf + (size_t)c * (RR * KK);
            const int d = c + 1;

            bf16x8 a[16];
            #pragma unroll
            for (int ms = 0; ms < 4; ++ms)
                #pragma unroll
                for (int kst = 0; kst < 4; ++kst)
                    a[ms * 4 + kst] = *(const bf16x8*)(
                        rin + (size_t)(m0 + ms * 16 + r16) * RR
                        + wave * 128 + kst * 32 + quad * 8);

            float zr[16];
            #pragma unroll
            for (int ms = 0; ms < 4; ++ms)
                #pragma unroll
                for (int r = 0; r < 4; ++r)
                    zr[ms * 4 + r] = z[(size_t)(m0 + ms * 16 + quad * 4 + r) * DD + d];

            #pragma unroll 1
            for (int h = 0; h < 2; ++h) {
                const int nb = nbb + h * 4;
                f32x4 acc[4][4];
                #pragma unroll
                for (int ms = 0; ms < 4; ++ms)
                    #pragma unroll
                    for (int sn = 0; sn < 4; ++sn)
                        acc[ms][sn] = f32x4{0.f, 0.f, 0.f, 0.f};

                const __hip_bfloat16* pB = tB + (size_t)nb * 2048
                                         + (size_t)wave * 4 * SKM
                                         + (size_t)lane * 8;
                bf16x8 bv[4][4];
                #pragma unroll
                for (int s = 0; s < 3; ++s)
                    #pragma unroll
                    for (int sn = 0; sn < 4; ++sn)
                        bv[s][sn] = *(const bf16x8*)(pB + (size_t)9 * PJM
                                                     + (size_t)s * SKM + sn * 512);

#define MFMA_STEP(SLOT)                                                        \
    _Pragma("unroll")                                                          \
    for (int ms = 0; ms < 4; ++ms)                                             \
        _Pragma("unroll")                                                      \
        for (int sn = 0; sn < 4; ++sn)                                         \
            acc[ms][sn] = __builtin_amdgcn_mfma_f32_16x16x32_bf16(             \
                a[ms * 4 + SLOT], bv[SLOT][sn], acc[ms][sn], 0, 0, 0);

                #pragma unroll 1
                for (int p = 0; p < 10; ++p) {
                    const int j = 9 - p;
                    if (p) {
                        #pragma unroll
                        for (int ms = 0; ms < 4; ++ms)
                            #pragma unroll
                            for (int sn = 0; sn < 4; ++sn)
                                #pragma unroll
                                for (int r = 0; r < 4; ++r)
                                    acc[ms][sn][r] *= zr[ms * 4 + r];
                    }
                    const size_t jb = (size_t)j * PJM;
                    #pragma unroll
                    for (int sn = 0; sn < 4; ++sn)
                        bv[3][sn] = *(const bf16x8*)(pB + jb + (size_t)3 * SKM + sn * 512);
                    MFMA_STEP(0)
                    if (p < 9) {
                        #pragma unroll
                        for (int sn = 0; sn < 4; ++sn)
                            bv[0][sn] = *(const bf16x8*)(pB + jb - PJM + sn * 512);
                    }
                    MFMA_STEP(1)
                    if (p < 9) {
                        #pragma unroll
                        for (int sn = 0; sn < 4; ++sn)
                            bv[1][sn] = *(const bf16x8*)(pB + jb - PJM + SKM + sn * 512);
                    }
                    MFMA_STEP(2)
                    if (p < 9) {
                        #pragma unroll
                        for (int sn = 0; sn < 4; ++sn)
                            bv[2][sn] = *(const bf16x8*)(pB + jb - PJM + 2 * SKM + sn * 512);
                    }
                    MFMA_STEP(3)
                }
#undef MFMA_STEP

                // ---- cross-wave K reduction (LDS reused -> leading sync) ----
                __syncthreads();
                if (wave & 1) {
                    const int idx = wave >> 1;
                    #pragma unroll
                    for (int i = 0; i < 16; ++i)
                        redp[idx * 1024 + i * 64 + lane] = acc[i >> 2][i & 3];
                }
                __syncthreads();
                if (wave == 0) {
                    #pragma unroll
                    for (int i = 0; i < 16; ++i)
                        acc[i >> 2][i & 3] += redp[i * 64 + lane];
                }
                if (wave == 2) {
                    #pragma unroll
                    for (int i = 0; i < 16; ++i) {
                        f32x4 t = acc[i >> 2][i & 3] + redp[1024 + i * 64 + lane];
                        redp[1024 + i * 64 + lane] = t;
                    }
                }
                __syncthreads();
                if (wave == 0) {
                    #pragma unroll
                    for (int i = 0; i < 16; ++i)
                        acc[i >> 2][i & 3] += redp[1024 + i * 64 + lane];
                    #pragma unroll
                    for (int ms = 0; ms < 4; ++ms)
                        #pragma unroll
                        for (int sn = 0; sn < 4; ++sn)
                            #pragma unroll
                            for (int r = 0; r < 4; ++r)
                                rc[(ms * 16 + quad * 4 + r) * 64 + sn * 16 + r16] =
                                    acc[ms][sn][r];
                }
                __syncthreads();
                {
                    const int row = tid >> 2, cg = (tid & 3) * 16;
                    #pragma unroll
                    for (int hh = 0; hh < 2; ++hh) {
                        union { __hip_bfloat16 h8[8]; uint4 u4; } pk;
                        #pragma unroll
                        for (int e = 0; e < 8; ++e)
                            pk.h8[e] = __float2bfloat16(rc[row * 64 + cg + hh * 8 + e]);
                        *(uint4*)(rout + (size_t)(m0 + row) * RR
                                  + nb * 64 + cg + hh * 8) = pk.u4;
                    }
                }
            }
            grid_sync(cnt, 2 + c);
        }
    }

    // ======================= Phase 8: last core ============================
    // 512 blocks x 16 rows, N=64, K split across 4 waves, f32 out.
    {
        f32x4* redp = (f32x4*)smraw;          // [2][4][64]
        float* rc   = (float*)smraw;          // [16][64]
        constexpr size_t SKL = 2048, PJL = 16 * SKL;
        const int m0 = bid * 16;
        const __hip_bfloat16* rin = resX;     // after 6 mids result is in resX

        bf16x8 a2[4];
        #pragma unroll
        for (int kst = 0; kst < 4; ++kst)
            a2[kst] = *(const bf16x8*)(rin + (size_t)(m0 + r16) * RR
                                       + wave * 128 + kst * 32 + quad * 8);
        float zl[4];
        #pragma unroll
        for (int r = 0; r < 4; ++r)
            zl[r] = z[(size_t)(m0 + quad * 4 + r) * DD + 7];

        f32x4 acc1[4];
        #pragma unroll
        for (int sn = 0; sn < 4; ++sn) acc1[sn] = f32x4{0.f, 0.f, 0.f, 0.f};

        const __hip_bfloat16* pB = tBlf + (size_t)wave * 4 * SKL + (size_t)lane * 8;
        bf16x8 bv[4][4];
        #pragma unroll
        for (int s = 0; s < 3; ++s)
            #pragma unroll
            for (int sn = 0; sn < 4; ++sn)
                bv[s][sn] = *(const bf16x8*)(pB + (size_t)9 * PJL
                                             + (size_t)s * SKL + sn * 512);

#define MFMA_STEPL(SLOT)                                                       \
    _Pragma("unroll")                                                          \
    for (int sn = 0; sn < 4; ++sn)                                             \
        acc1[sn] = __builtin_amdgcn_mfma_f32_16x16x32_bf16(                    \
            a2[SLOT], bv[SLOT][sn], acc1[sn], 0, 0, 0);

        #pragma unroll 1
        for (int p = 0; p < 10; ++p) {
            const int j = 9 - p;
            if (p) {
                #pragma unroll
                for (int sn = 0; sn < 4; ++sn)
                    #pragma unroll
                    for (int r = 0; r < 4; ++r)
                        acc1[sn][r] *= zl[r];
            }
            const size_t jb = (size_t)j * PJL;
            #pragma unroll
            for (int sn = 0; sn < 4; ++sn)
                bv[3][sn] = *(const bf16x8*)(pB + jb + (size_t)3 * SKL + sn * 512);
            MFMA_STEPL(0)
            if (p < 9) {
                #pragma unroll
                for (int sn = 0; sn < 4; ++sn)
                    bv[0][sn] = *(const bf16x8*)(pB + jb - PJL + sn * 512);
            }
            MFMA_STEPL(1)
            if (p < 9) {
                #pragma unroll
                for (int sn = 0; sn < 4; ++sn)
                    bv[1][sn] = *(const bf16x8*)(pB + jb - PJL + SKL + sn * 512);
            }
            MFMA_STEPL(2)
            if (p < 9) {
                #pragma unroll
                for (int sn = 0; sn < 4; ++sn)
                    bv[2][sn] = *(const bf16x8*)(pB + jb - PJL + 2 * SKL + sn * 512);
            }
            MFMA_STEPL(3)
        }
#undef MFMA_STEPL

        __syncthreads();
        if (wave & 1) {
            const int idx = wave >> 1;
            #pragma unroll
            for (int i = 0; i < 4; ++i) redp[idx * 256 + i * 64 + lane] = acc1[i];
        }
        __syncthreads();
        if (wave == 0) {
            #pragma unroll
            for (int i = 0; i < 4; ++i) acc1[i] += redp[i * 64 + lane];
        }
        if (wave == 2) {
            #pragma unroll
            for (int i = 0; i < 4; ++i) {
                f32x4 t = acc1[i] + redp[256 + i * 64 + lane];
                redp[256 + i * 64 + lane] = t;
            }
        }
        __syncthreads();
        if (wave == 0) {
            #pragma unroll
            for (int i = 0; i < 4; ++i) acc1[i] += redp[256 + i * 64 + lane];
            #pragma unroll
            for (int sn = 0; sn < 4; ++sn)
                #pragma unroll
                for (int r = 0; r < 4; ++r)
                    rc[(quad * 4 + r) * 64 + sn * 16 + r16] = acc1[sn][r];
        }
        __syncthreads();
        {
            const int row = tid >> 4, col = (tid & 15) * 4;
            *(f32x4*)(out + (size_t)(m0 + row) * OUTD + col) =
                *(const f32x4*)(rc + row * 64 + col);
        }
    }
}

// ---------------------------------------------------------------------------
extern "C" void kernel_launch(void* const* d_in, const int* in_sizes, int n_in,
                              void* d_out, int out_size, void* d_ws, size_t ws_size,
                              hipStream_t stream) {
    const float* z     = (const float*)d_in[0];
    const float* G0    = (const float*)d_in[1];
    const float* Gmid  = (const float*)d_in[2];
    const float* Glast = (const float*)d_in[3];
    float* out = (float*)d_out;

    char* ws = (char*)d_ws;
    __hip_bfloat16* resX = (__hip_bfloat16*)ws;                          // 8 MB
    __hip_bfloat16* resY = (__hip_bfloat16*)(ws + ((size_t)8 << 20));    // 8 MB
    __hip_bfloat16* tBf  = (__hip_bfloat16*)(ws + ((size_t)16 << 20));   // 31.5 MB
    __hip_bfloat16* tBlf = (__hip_bfloat16*)(ws + ((size_t)48 << 20));   // 640 KB
    float* tG0           = (float*)(ws + ((size_t)49 << 20));            // 20 KB
    int* cnt             = (int*)(ws + ((size_t)50 << 20));              // 64 B

    hipMemsetAsync(cnt, 0, 64, stream);
    tt_mega<<<dim3(NBLK), dim3(256), 0, stream>>>(
        z, G0, Gmid, Glast, out, resX, resY, tBf, tBlf, tG0, cnt);
}

// Round 11
// 434.674 us; speedup vs baseline: 2.2799x; 2.2799x over previous
//
#include <hip/hip_runtime.h>
#include <hip/hip_bf16.h>
#include <stdint.h>

// Problem constants
#define BB   8192   // batch
#define DD   8      // features
#define PP   10     // poly basis width
#define RR   512    // TT rank
#define OUTD 64     // output dim
#define KK   5120   // expanded K = PP*RR

typedef __bf16 bf16x8 __attribute__((ext_vector_type(8)));
typedef float  f32x4  __attribute__((ext_vector_type(4)));

template <bool NT>
__device__ __forceinline__ bf16x8 ldb(const __hip_bfloat16* p) {
    if constexpr (NT) return __builtin_nontemporal_load((const bf16x8*)p);
    else              return *(const bf16x8*)p;
}

// ---------------------------------------------------------------------------
// Fused prep (one launch): grid 971 blocks x 256.
//   u < 960 : mid-core fragment pack, unit = (c,j,kc): 32 i-rows x 512 n.
//   960..969: last-core fragment pack, unit = j (loops kc internally).
//   970     : tanh(G0) (5120 elems).
// Fragment-linear layout (verified r6-r8): dst[(j*16+kc)*32N + nt*512+lane*8+e]
//   n = nt*16 + (lane&15), i = kc*32 + (lane>>4)*8 + e
// ---------------------------------------------------------------------------
__global__ __launch_bounds__(256) void prep_fused(
        const float* __restrict__ Gmid, const float* __restrict__ Glast,
        const float* __restrict__ G0,
        __hip_bfloat16* __restrict__ tBf, __hip_bfloat16* __restrict__ tBlf,
        float* __restrict__ tG0) {
    __shared__ __hip_bfloat16 sT[32 * 520];
    const int u = blockIdx.x, tid = threadIdx.x;
    if (u < 960) {
        const int c = u / 160, rem = u - c * 160;
        const int j = rem >> 4, kc = rem & 15;
        const float* Gp = Gmid + (size_t)c * (512 * 5120);
        __hip_bfloat16* db = tBf + (size_t)c * (RR * KK)
                           + (size_t)(j * 16 + kc) * 16384;
        #pragma unroll
        for (int e = 0; e < 16; ++e) {
            const int idx = (e * 256 + tid) * 4;
            const int row = idx >> 9, col = idx & 511;
            f32x4 v = *(const f32x4*)(Gp + (size_t)(kc * 32 + row) * 5120
                                      + (size_t)j * 512 + col);
            __hip_bfloat16* sp = sT + row * 520 + col;
            sp[0] = __float2bfloat16(tanhf(v.x));
            sp[1] = __float2bfloat16(tanhf(v.y));
            sp[2] = __float2bfloat16(tanhf(v.z));
            sp[3] = __float2bfloat16(tanhf(v.w));
        }
        __syncthreads();
        #pragma unroll
        for (int cc = 0; cc < 8; ++cc) {
            const int ch = cc * 256 + tid;
            const int nt = ch >> 6, l = ch & 63;
            const int r0 = (l >> 4) * 8, cb = nt * 16 + (l & 15);
            union { __hip_bfloat16 h[8]; uint4 u4; } pk;
            #pragma unroll
            for (int e = 0; e < 8; ++e) pk.h[e] = sT[(r0 + e) * 520 + cb];
            *(uint4*)(db + (size_t)ch * 8) = pk.u4;
        }
    } else if (u < 970) {
        const int j = u - 960;
        #pragma unroll 1
        for (int kc = 0; kc < 16; ++kc) {
            __syncthreads();
            #pragma unroll
            for (int it = 0; it < 2; ++it) {
                const int idx = (it * 256 + tid) * 4;
                const int row = idx >> 6, col = idx & 63;
                f32x4 v = *(const f32x4*)(Glast + (size_t)(kc * 32 + row) * 640
                                          + (size_t)j * 64 + col);
                __hip_bfloat16* sp = sT + row * 72 + col;
                sp[0] = __float2bfloat16(tanhf(v.x));
                sp[1] = __float2bfloat16(tanhf(v.y));
                sp[2] = __float2bfloat16(tanhf(v.z));
                sp[3] = __float2bfloat16(tanhf(v.w));
            }
            __syncthreads();
            {
                const int ch = tid;
                const int nt = ch >> 6, l = ch & 63;
                const int r0 = (l >> 4) * 8, cb = nt * 16 + (l & 15);
                union { __hip_bfloat16 h[8]; uint4 u4; } pk;
                #pragma unroll
                for (int e = 0; e < 8; ++e) pk.h[e] = sT[(r0 + e) * 72 + cb];
                *(uint4*)(tBlf + (size_t)(j * 16 + kc) * 2048 + (size_t)ch * 8) = pk.u4;
            }
        }
    } else {
        for (int x = tid; x < 5120; x += 256) tG0[x] = tanhf(G0[x]);
    }
}

// ---------------------------------------------------------------------------
// First core: res0[b,r] = Horner_j( tG0[j,r]; z[b,0] ) -> bf16
// ---------------------------------------------------------------------------
__global__ __launch_bounds__(512) void tt_first(
        const float* __restrict__ z, const float* __restrict__ tG0,
        __hip_bfloat16* __restrict__ res0) {
    const int r = threadIdx.x;
    const int b0 = blockIdx.x * 32;
    float tg[10];
    #pragma unroll
    for (int j = 0; j < 10; ++j) tg[j] = tG0[j * RR + r];
    #pragma unroll 1
    for (int b = 0; b < 32; ++b) {
        const float z0 = z[(size_t)(b0 + b) * DD];
        float acc = tg[9];
        #pragma unroll
        for (int j = 8; j >= 0; --j) acc = acc * z0 + tg[j];
        res0[(size_t)(b0 + b) * RR + r] = __float2bfloat16(acc);
    }
}

// ---------------------------------------------------------------------------
// Horner GEMM, K split across waves, depth-3 B register prefetch ring.
// EXACT round-8 structure (best measured: 47us/mid, 388us total), plus a
// compile-time NTB switch: non-temporal B loads (B has ZERO intra-block
// reuse -> every B load is an L1 compulsory miss; nt bypasses L1 alloc).
//   MID (MT=4): grid (128, 8): m0 = bx*64, nb = by. Chunked XCD dispatch
//   (evidence r8 vs r9) pins one 640KB B-column per XCD's L2.
//   LAST (MT=2): grid 256 1-D, nb=0, f32 out.
//   All fragment arrays compile-time indexed (r4 lesson: dynamic -> scratch).
// ---------------------------------------------------------------------------
template <bool LASTV, int NTOT, int MT, bool NTB>
__global__ __launch_bounds__(256, 2) void tt_gemm_ks(
        const __hip_bfloat16* __restrict__ resin,
        const __hip_bfloat16* __restrict__ tBf,
        void* __restrict__ outp,
        const float* __restrict__ z, int d) {
    __shared__ f32x4 red[2][MT * 4][64];

    const int tid  = threadIdx.x;
    const int lane = tid & 63;
    const int wave = tid >> 6;
    const int m0 = LASTV ? blockIdx.x * (MT * 16) : blockIdx.x * 64;
    const int nb = LASTV ? 0 : blockIdx.y;
    const int r16 = lane & 15, quad = lane >> 4;

    bf16x8 a[MT * 4];
    #pragma unroll
    for (int ms = 0; ms < MT; ++ms)
        #pragma unroll
        for (int kst = 0; kst < 4; ++kst)
            a[ms * 4 + kst] = *(const bf16x8*)(
                resin + (size_t)(m0 + ms * 16 + r16) * RR + wave * 128 + kst * 32 + quad * 8);

    float zr[MT * 4];
    #pragma unroll
    for (int ms = 0; ms < MT; ++ms)
        #pragma unroll
        for (int r = 0; r < 4; ++r)
            zr[ms * 4 + r] = z[(size_t)(m0 + ms * 16 + quad * 4 + r) * DD + d];

    f32x4 acc[MT][4];
    #pragma unroll
    for (int ms = 0; ms < MT; ++ms)
        #pragma unroll
        for (int sn = 0; sn < 4; ++sn) acc[ms][sn] = f32x4{0.f, 0.f, 0.f, 0.f};

    constexpr size_t SK = (size_t)NTOT * 512;
    constexpr size_t PJ = 16 * SK;
    const __hip_bfloat16* pB = tBf + (size_t)nb * 4 * 512
                             + (size_t)wave * 4 * SK + (size_t)lane * 8;

    bf16x8 bv[4][4];
    #pragma unroll
    for (int s = 0; s < 3; ++s)
        #pragma unroll
        for (int sn = 0; sn < 4; ++sn)
            bv[s][sn] = ldb<NTB>(pB + (size_t)9 * PJ + (size_t)s * SK + sn * 512);

#define MFMA_STEP(SLOT)                                                        \
    _Pragma("unroll")                                                          \
    for (int ms = 0; ms < MT; ++ms)                                            \
        _Pragma("unroll")                                                      \
        for (int sn = 0; sn < 4; ++sn)                                         \
            acc[ms][sn] = __builtin_amdgcn_mfma_f32_16x16x32_bf16(             \
                a[ms * 4 + SLOT], bv[SLOT][sn], acc[ms][sn], 0, 0, 0);

    #pragma unroll 1
    for (int p = 0; p < 10; ++p) {
        const int j = 9 - p;
        if (p) {
            #pragma unroll
            for (int ms = 0; ms < MT; ++ms)
                #pragma unroll
                for (int sn = 0; sn < 4; ++sn)
                    #pragma unroll
                    for (int r = 0; r < 4; ++r)
                        acc[ms][sn][r] *= zr[ms * 4 + r];
        }
        const size_t jb = (size_t)j * PJ;
        #pragma unroll
        for (int sn = 0; sn < 4; ++sn)
            bv[3][sn] = ldb<NTB>(pB + jb + (size_t)3 * SK + sn * 512);
        MFMA_STEP(0)
        if (p < 9) {
            #pragma unroll
            for (int sn = 0; sn < 4; ++sn)
                bv[0][sn] = ldb<NTB>(pB + jb - PJ + sn * 512);
        }
        MFMA_STEP(1)
        if (p < 9) {
            #pragma unroll
            for (int sn = 0; sn < 4; ++sn)
                bv[1][sn] = ldb<NTB>(pB + jb - PJ + SK + sn * 512);
        }
        MFMA_STEP(2)
        if (p < 9) {
            #pragma unroll
            for (int sn = 0; sn < 4; ++sn)
                bv[2][sn] = ldb<NTB>(pB + jb - PJ + 2 * SK + sn * 512);
        }
        MFMA_STEP(3)
    }
#undef MFMA_STEP

    // ---- cross-wave K reduction ----
    if (wave & 1) {
        const int idx = wave >> 1;
        #pragma unroll
        for (int i = 0; i < MT * 4; ++i) red[idx][i][lane] = acc[i >> 2][i & 3];
    }
    __syncthreads();
    if (wave == 0) {
        #pragma unroll
        for (int i = 0; i < MT * 4; ++i) acc[i >> 2][i & 3] += red[0][i][lane];
    }
    if (wave == 2) {
        #pragma unroll
        for (int i = 0; i < MT * 4; ++i) {
            f32x4 t = acc[i >> 2][i & 3] + red[1][i][lane];
            red[1][i][lane] = t;
        }
    }
    __syncthreads();
    float* rc = (float*)&red[0][0][0];
    if (wave == 0) {
        #pragma unroll
        for (int i = 0; i < MT * 4; ++i) acc[i >> 2][i & 3] += red[1][i][lane];
        #pragma unroll
        for (int ms = 0; ms < MT; ++ms)
            #pragma unroll
            for (int sn = 0; sn < 4; ++sn)
                #pragma unroll
                for (int r = 0; r < 4; ++r)
                    rc[(ms * 16 + quad * 4 + r) * 64 + sn * 16 + r16] = acc[ms][sn][r];
    }
    __syncthreads();

    if (LASTV) {
        float* o = (float*)outp;
        const int row = tid >> 3, cg = (tid & 7) * 8;
        #pragma unroll
        for (int q = 0; q < 2; ++q)
            *(f32x4*)(o + (size_t)(m0 + row) * OUTD + cg + q * 4) =
                *(const f32x4*)(rc + row * 64 + cg + q * 4);
    } else {
        __hip_bfloat16* o = (__hip_bfloat16*)outp;
        const int row = tid >> 2, cg = (tid & 3) * 16;
        #pragma unroll
        for (int h = 0; h < 2; ++h) {
            union { __hip_bfloat16 hh[8]; uint4 u; } pk;
            #pragma unroll
            for (int e = 0; e < 8; ++e)
                pk.hh[e] = __float2bfloat16(rc[row * 64 + cg + h * 8 + e]);
            *(uint4*)(o + (size_t)(m0 + row) * RR + nb * 64 + cg + h * 8) = pk.u;
        }
    }
}

// ---------------------------------------------------------------------------
extern "C" void kernel_launch(void* const* d_in, const int* in_sizes, int n_in,
                              void* d_out, int out_size, void* d_ws, size_t ws_size,
                              hipStream_t stream) {
    const float* z     = (const float*)d_in[0];
    const float* G0    = (const float*)d_in[1];
    const float* Gmid  = (const float*)d_in[2];
    const float* Glast = (const float*)d_in[3];
    float* out = (float*)d_out;

    char* ws = (char*)d_ws;
    __hip_bfloat16* resX = (__hip_bfloat16*)ws;                          // 8 MB
    __hip_bfloat16* resY = (__hip_bfloat16*)(ws + ((size_t)8 << 20));    // 8 MB
    __hip_bfloat16* tBf  = (__hip_bfloat16*)(ws + ((size_t)16 << 20));   // 31.5 MB
    __hip_bfloat16* tBlf = (__hip_bfloat16*)(ws + ((size_t)48 << 20));   // 640 KB
    float* tG0           = (float*)(ws + ((size_t)49 << 20));            // 20 KB

    prep_fused<<<dim3(971), 256, 0, stream>>>(Gmid, Glast, G0, tBf, tBlf, tG0);
    tt_first<<<dim3(BB / 32), 512, 0, stream>>>(z, tG0, resX);

    __hip_bfloat16* rin = resX;
    __hip_bfloat16* rnext = resY;
    for (int c = 0; c < 6; ++c) {
        if (c & 1)
            tt_gemm_ks<false, 32, 4, true><<<dim3(BB / 64, RR / 64), 256, 0, stream>>>(
                rin, tBf + (size_t)c * RR * KK, rnext, z, c + 1);
        else
            tt_gemm_ks<false, 32, 4, false><<<dim3(BB / 64, RR / 64), 256, 0, stream>>>(
                rin, tBf + (size_t)c * RR * KK, rnext, z, c + 1);
        __hip_bfloat16* t = rin; rin = rnext; rnext = t;
    }
    tt_gemm_ks<true, 4, 2, false><<<dim3(BB / 32), 256, 0, stream>>>(
        rin, tBlf, out, z, 7);
}